// Round 3
// baseline (724.709 us; speedup 1.0000x reference)
//
#include <hip/hip_runtime.h>
#include <stdint.h>

#define N_TOK 4096
#define TOPK  2
#define NEXP  8
#define HID   2048
#define INTER 1408
#define NSLOT (N_TOK * TOPK)     // 8192 token-expert pairs
#define PADROWS 128              // guard rows for tile-overrun reads
#define WELEM (NEXP * INTER * HID)
#define MAXTILES 72              // worst-case sum of ceil(cnt_e/128)
#define NCOL_G (INTER / 128)     // 11 col strips, gate/up
#define NCOL_D (HID / 128)       // 16 col strips, down
#define NSTRIP_G (NEXP * NCOL_G) // 88
#define NSTRIP_D (NEXP * NCOL_D) // 128
#define CAP 160                  // per-XCD-residue block capacity (worst case 128+slack)
#define GSCHED (8 * CAP)         // 1280 scheduled block slots per GEMM

typedef _Float16 half8 __attribute__((ext_vector_type(8)));
typedef float floatx4 __attribute__((ext_vector_type(4)));

__device__ __forceinline__ void gld_lds16(const void* g, void* l) {
  // async global->LDS, 16B/lane; LDS dest = wave-uniform base + lane*16
  __builtin_amdgcn_global_load_lds(
      (const __attribute__((address_space(1))) uint32_t*)g,
      (__attribute__((address_space(3))) uint32_t*)l, 16, 0, 0);
}

// s_waitcnt imm encodings (gfx9-style): vmcnt[3:0]+[15:14], exp[6:4], lgkm[11:8]
#define WAITCNT_VM6   0x0F76   // vmcnt(6)
#define WAITCNT_VM4   0x0F74   // vmcnt(4)
#define WAITCNT_VM0   0x0F70   // vmcnt(0)
#define WAITCNT_LGKM0 0xC07F   // lgkmcnt(0)
#define RAW_BARRIER() asm volatile("s_barrier" ::: "memory")

// ------- routing: slot lists, tile table, XCD-local block schedules -------
// sched entry: (col_strip << 16) | tile_index, -1 = dead block.
// Placement: gid -> XCD gid%8 (round-robin heuristic). All row-tiles of one
// (expert, col-strip) B-reuse unit sit consecutively on ONE residue so the
// strip stays in that XCD's L2.
__global__ void route_kernel(const int* __restrict__ ids, const float* __restrict__ tw,
                             int* __restrict__ tinfo, int* __restrict__ stok,
                             int* __restrict__ inv,
                             int* __restrict__ schedG, int* __restrict__ schedD) {
  __shared__ int tc[NEXP][257];
  __shared__ int eo[NEXP + 1];
  __shared__ int s_ft[NEXP], s_nt[NEXP];
  __shared__ short g_x[NSTRIP_G], g_cx[NSTRIP_G];
  __shared__ int   g_b[NSTRIP_G], g_ft[NSTRIP_G], g_n[NSTRIP_G];
  __shared__ short d_x[NSTRIP_D], d_cx[NSTRIP_D];
  __shared__ int   d_b[NSTRIP_D], d_ft[NSTRIP_D], d_n[NSTRIP_D];
  __shared__ int nsg, nsd;
  const int t = threadIdx.x;
  int lc[NEXP];
#pragma unroll
  for (int e = 0; e < NEXP; e++) lc[e] = 0;
  for (int i = 0; i < NSLOT / 256; i++) {
    int e = ids[t + 256 * i];
#pragma unroll
    for (int q = 0; q < NEXP; q++) lc[q] += (e == q) ? 1 : 0;
  }
#pragma unroll
  for (int e = 0; e < NEXP; e++) tc[e][t + 1] = lc[e];
  if (t < NEXP) tc[t][0] = 0;
  __syncthreads();
  if (t < NEXP) {  // serial scan per expert
    int run = 0;
    for (int i = 0; i <= 256; i++) { run += tc[t][i]; tc[t][i] = run; }
  }
  __syncthreads();
  if (t == 0) {
    eo[0] = 0;
    for (int e = 0; e < NEXP; e++) eo[e + 1] = eo[e] + tc[e][256];
    int nt = 0;
    for (int e = 0; e < NEXP; e++) {
      const int c = tc[e][256];
      s_ft[e] = nt;
      for (int r0 = 0; r0 < c; r0 += 128) {
        tinfo[1 + 3 * nt] = e;
        tinfo[2 + 3 * nt] = eo[e] + r0;
        tinfo[3 + 3 * nt] = (c - r0 < 128) ? (c - r0) : 128;
        nt++;
      }
      s_nt[e] = nt - s_ft[e];
    }
    tinfo[0] = nt;
    // greedy bin-pack strips onto 8 XCD residues
    int loadg[8], loadd[8];
    for (int x = 0; x < 8; x++) { loadg[x] = 0; loadd[x] = 0; }
    int sg = 0, sd = 0;
    for (int e = 0; e < NEXP; e++) {
      const int n = s_nt[e];
      if (n == 0) continue;
      for (int cx = 0; cx < NCOL_G; cx++) {
        int best = 0;
        for (int x = 1; x < 8; x++) if (loadg[x] < loadg[best]) best = x;
        g_x[sg] = (short)best; g_cx[sg] = (short)cx;
        g_b[sg] = loadg[best]; g_ft[sg] = s_ft[e]; g_n[sg] = n;
        loadg[best] += n; sg++;
      }
      for (int cx = 0; cx < NCOL_D; cx++) {
        int best = 0;
        for (int x = 1; x < 8; x++) if (loadd[x] < loadd[best]) best = x;
        d_x[sd] = (short)best; d_cx[sd] = (short)cx;
        d_b[sd] = loadd[best]; d_ft[sd] = s_ft[e]; d_n[sd] = n;
        loadd[best] += n; sd++;
      }
    }
    nsg = sg; nsd = sd;
  }
  __syncthreads();
  for (int i = t; i < GSCHED; i += 256) { schedG[i] = -1; schedD[i] = -1; }
  __syncthreads();
  for (int s = 0; s < nsg; s++)
    for (int i = t; i < g_n[s]; i += 256) {
      int slot = g_b[s] + i;
      if (slot < CAP) schedG[slot * 8 + g_x[s]] = ((int)g_cx[s] << 16) | (g_ft[s] + i);
    }
  for (int s = 0; s < nsd; s++)
    for (int i = t; i < d_n[s]; i += 256) {
      int slot = d_b[s] + i;
      if (slot < CAP) schedD[slot * 8 + d_x[s]] = ((int)d_cx[s] << 16) | (d_ft[s] + i);
    }
  // compact slot lists + inverse map
  int pos[NEXP];
#pragma unroll
  for (int e = 0; e < NEXP; e++) pos[e] = eo[e] + tc[e][t];
  for (int i = 0; i < NSLOT / 256; i++) {
    int s = t + 256 * i;
    int e = ids[s];
    int p = 0;
#pragma unroll
    for (int q = 0; q < NEXP; q++)
      if (e == q) p = pos[q]++;
    stok[p] = s / TOPK;
    inv[s] = p;
  }
}

// ---------------- gather tokens into contiguous fp16 A ----------------
__global__ void gather_x_kernel(const float* __restrict__ x, const int* __restrict__ stok,
                                _Float16* __restrict__ xg) {
  const int row = blockIdx.x;
  const int tok = stok[row];
  const float4* src = (const float4*)(x + (size_t)tok * HID);
  half8* dst = (half8*)(xg + (size_t)row * HID);
  const int t = threadIdx.x;
  float4 a = src[2 * t], b = src[2 * t + 1];
  half8 h;
  h[0] = (_Float16)a.x; h[1] = (_Float16)a.y; h[2] = (_Float16)a.z; h[3] = (_Float16)a.w;
  h[4] = (_Float16)b.x; h[5] = (_Float16)b.y; h[6] = (_Float16)b.z; h[7] = (_Float16)b.w;
  dst[t] = h;
}

// ---------------- fp32 -> fp16 weight conversion, all 3 matrices ----------------
__global__ void convert3_kernel(const float* __restrict__ s0, const float* __restrict__ s1,
                                const float* __restrict__ s2, _Float16* __restrict__ d0,
                                _Float16* __restrict__ d1, _Float16* __restrict__ d2) {
  const float* s = blockIdx.z == 0 ? s0 : (blockIdx.z == 1 ? s1 : s2);
  _Float16* d = blockIdx.z == 0 ? d0 : (blockIdx.z == 1 ? d1 : d2);
  const int j = (blockIdx.x * 256 + threadIdx.x) * 8;
  float4 a = *(const float4*)(s + j);
  float4 b = *(const float4*)(s + j + 4);
  half8 h;
  h[0] = (_Float16)a.x; h[1] = (_Float16)a.y; h[2] = (_Float16)a.z; h[3] = (_Float16)a.w;
  h[4] = (_Float16)b.x; h[5] = (_Float16)b.y; h[6] = (_Float16)b.z; h[7] = (_Float16)b.w;
  *(half8*)(d + j) = h;
}

// ---------------- fused gate+up GEMM with SwiGLU epilogue ----------------
__global__ __launch_bounds__(256, 3) void gateup_kernel(
    const _Float16* __restrict__ A, const _Float16* __restrict__ Bg,
    const _Float16* __restrict__ Bu, _Float16* __restrict__ H,
    const int* __restrict__ tinfo, const int* __restrict__ sched) {
  const int ent = sched[blockIdx.x];
  if (ent < 0) return;
  const int ti   = ent & 0xFFFF;
  const int e    = tinfo[1 + 3 * ti];
  const int row0 = tinfo[2 + 3 * ti];
  const int mrem = tinfo[3 + 3 * ti];
  const int col0 = (ent >> 16) * 128;
  const _Float16* Bge = Bg + (size_t)e * INTER * HID;
  const _Float16* Bue = Bu + (size_t)e * INTER * HID;

  __shared__ __align__(16) _Float16 As[2][128 * 32];
  __shared__ __align__(16) _Float16 Bgs[2][128 * 32];
  __shared__ __align__(16) _Float16 Bus[2][128 * 32];

  const int tid = threadIdx.x;
  const int wave = tid >> 6, lane = tid & 63;
  const int quad = lane >> 4, l16 = lane & 15;
  const int wm = (wave >> 1) * 64, wn = (wave & 1) * 64;

  const int bo0 = wave * 2048 + lane * 16, bo1 = bo0 + 1024;
  const int ar0 = bo0 >> 6, ak0 = (bo0 & 63) >> 1;
  const int ar1 = bo1 >> 6, ak1 = (bo1 & 63) >> 1;
  const _Float16* Ab0 = A + (size_t)(row0 + ar0) * HID + ak0;
  const _Float16* Ab1 = A + (size_t)(row0 + ar1) * HID + ak1;
  const _Float16* Bg0 = Bge + (size_t)(col0 + ar0) * HID + ak0;
  const _Float16* Bg1 = Bge + (size_t)(col0 + ar1) * HID + ak1;
  const _Float16* Bu0 = Bue + (size_t)(col0 + ar0) * HID + ak0;
  const _Float16* Bu1 = Bue + (size_t)(col0 + ar1) * HID + ak1;

  floatx4 ag[4][4], au[4][4];
#pragma unroll
  for (int a = 0; a < 4; a++)
#pragma unroll
    for (int b = 0; b < 4; b++) {
      ag[a][b] = (floatx4){0.f, 0.f, 0.f, 0.f};
      au[a][b] = (floatx4){0.f, 0.f, 0.f, 0.f};
    }

  auto stage = [&](int kt, int buf) {  // 6 vmem issues per wave
    const int k0 = kt * 32;
    char* as = (char*)(As[buf]) + wave * 2048;
    char* bg = (char*)(Bgs[buf]) + wave * 2048;
    char* bu = (char*)(Bus[buf]) + wave * 2048;
    gld_lds16(Ab0 + k0, as);
    gld_lds16(Ab1 + k0, as + 1024);
    gld_lds16(Bg0 + k0, bg);
    gld_lds16(Bg1 + k0, bg + 1024);
    gld_lds16(Bu0 + k0, bu);
    gld_lds16(Bu1 + k0, bu + 1024);
  };

  const int NKI = HID / 32;  // 64
  stage(0, 0);
  stage(1, 1);
  for (int kt = 0; kt < NKI; ++kt) {
    const int buf = kt & 1;
    if (kt < NKI - 1) __builtin_amdgcn_s_waitcnt(WAITCNT_VM6);
    else              __builtin_amdgcn_s_waitcnt(WAITCNT_VM0);
    RAW_BARRIER();  // stage(kt) visible; prefetch stays in flight
    half8 af[4], bgf[4], buf_[4];
#pragma unroll
    for (int i = 0; i < 4; ++i) {
      af[i]   = *(const half8*)(As[buf]  + (wm + i * 16 + l16) * 32 + quad * 8);
      bgf[i]  = *(const half8*)(Bgs[buf] + (wn + i * 16 + l16) * 32 + quad * 8);
      buf_[i] = *(const half8*)(Bus[buf] + (wn + i * 16 + l16) * 32 + quad * 8);
    }
    __builtin_amdgcn_s_waitcnt(WAITCNT_LGKM0);
    RAW_BARRIER();
    if (kt + 2 < NKI) stage(kt + 2, buf);
#pragma unroll
    for (int mi = 0; mi < 4; ++mi)
#pragma unroll
      for (int ni = 0; ni < 4; ++ni) {
        ag[mi][ni] = __builtin_amdgcn_mfma_f32_16x16x32_f16(af[mi], bgf[ni], ag[mi][ni], 0, 0, 0);
        au[mi][ni] = __builtin_amdgcn_mfma_f32_16x16x32_f16(af[mi], buf_[ni], au[mi][ni], 0, 0, 0);
      }
  }

  // D mapping (m89): col = lane&15, row = quad*4 + reg
#pragma unroll
  for (int mi = 0; mi < 4; ++mi)
#pragma unroll
    for (int r = 0; r < 4; ++r) {
      const int rm = wm + mi * 16 + quad * 4 + r;
      if (rm < mrem) {
        _Float16* hrow = H + (size_t)(row0 + rm) * INTER + col0 + wn;
#pragma unroll
        for (int ni = 0; ni < 4; ++ni) {
          float g = ag[mi][ni][r], u = au[mi][ni][r];
          float s = 1.0f / (1.0f + __expf(-g));
          hrow[ni * 16 + l16] = (_Float16)(g * s * u);
        }
      }
    }
}

// ---------------- down GEMM, plain per-slot fp16 store ----------------
__global__ __launch_bounds__(256, 4) void down_kernel(
    const _Float16* __restrict__ A, const _Float16* __restrict__ B,
    _Float16* __restrict__ Ds, const int* __restrict__ tinfo,
    const int* __restrict__ sched) {
  const int ent = sched[blockIdx.x];
  if (ent < 0) return;
  const int ti   = ent & 0xFFFF;
  const int e    = tinfo[1 + 3 * ti];
  const int row0 = tinfo[2 + 3 * ti];
  const int mrem = tinfo[3 + 3 * ti];
  const int col0 = (ent >> 16) * 128;
  const _Float16* Be = B + (size_t)e * HID * INTER;

  __shared__ __align__(16) _Float16 As[2][128 * 32];
  __shared__ __align__(16) _Float16 Bs[2][128 * 32];

  const int tid = threadIdx.x;
  const int wave = tid >> 6, lane = tid & 63;
  const int quad = lane >> 4, l16 = lane & 15;
  const int wm = (wave >> 1) * 64, wn = (wave & 1) * 64;

  const int bo0 = wave * 2048 + lane * 16, bo1 = bo0 + 1024;
  const int ar0 = bo0 >> 6, ak0 = (bo0 & 63) >> 1;
  const int ar1 = bo1 >> 6, ak1 = (bo1 & 63) >> 1;
  const _Float16* Ab0 = A + (size_t)(row0 + ar0) * INTER + ak0;
  const _Float16* Ab1 = A + (size_t)(row0 + ar1) * INTER + ak1;
  const _Float16* Bb0 = Be + (size_t)(col0 + ar0) * INTER + ak0;
  const _Float16* Bb1 = Be + (size_t)(col0 + ar1) * INTER + ak1;

  floatx4 acc[4][4];
#pragma unroll
  for (int a = 0; a < 4; a++)
#pragma unroll
    for (int b = 0; b < 4; b++) acc[a][b] = (floatx4){0.f, 0.f, 0.f, 0.f};

  auto stage = [&](int kt, int buf) {  // 4 vmem issues per wave
    const int k0 = kt * 32;
    char* as = (char*)(As[buf]) + wave * 2048;
    char* bs = (char*)(Bs[buf]) + wave * 2048;
    gld_lds16(Ab0 + k0, as);
    gld_lds16(Ab1 + k0, as + 1024);
    gld_lds16(Bb0 + k0, bs);
    gld_lds16(Bb1 + k0, bs + 1024);
  };

  const int NKI = INTER / 32;  // 44
  stage(0, 0);
  stage(1, 1);
  for (int kt = 0; kt < NKI; ++kt) {
    const int buf = kt & 1;
    if (kt < NKI - 1) __builtin_amdgcn_s_waitcnt(WAITCNT_VM4);
    else              __builtin_amdgcn_s_waitcnt(WAITCNT_VM0);
    RAW_BARRIER();
    half8 af[4], bf[4];
#pragma unroll
    for (int i = 0; i < 4; ++i) {
      af[i] = *(const half8*)(As[buf] + (wm + i * 16 + l16) * 32 + quad * 8);
      bf[i] = *(const half8*)(Bs[buf] + (wn + i * 16 + l16) * 32 + quad * 8);
    }
    __builtin_amdgcn_s_waitcnt(WAITCNT_LGKM0);
    RAW_BARRIER();
    if (kt + 2 < NKI) stage(kt + 2, buf);
#pragma unroll
    for (int mi = 0; mi < 4; ++mi)
#pragma unroll
      for (int ni = 0; ni < 4; ++ni)
        acc[mi][ni] = __builtin_amdgcn_mfma_f32_16x16x32_f16(af[mi], bf[ni], acc[mi][ni], 0, 0, 0);
  }

#pragma unroll
  for (int mi = 0; mi < 4; ++mi)
#pragma unroll
    for (int r = 0; r < 4; ++r) {
      const int rm = wm + mi * 16 + quad * 4 + r;
      if (rm < mrem) {
        _Float16* drow = Ds + (size_t)(row0 + rm) * HID + col0 + wn;
#pragma unroll
        for (int ni = 0; ni < 4; ++ni) drow[ni * 16 + l16] = (_Float16)acc[mi][ni][r];
      }
    }
}

// ---------------- combine: out[tok] = w0*Ds[p0] + w1*Ds[p1] ----------------
__global__ void combine_kernel(const _Float16* __restrict__ Ds, const int* __restrict__ inv,
                               const float* __restrict__ tw, float* __restrict__ out) {
  const int tok = blockIdx.x, t = threadIdx.x;
  const int p0 = inv[2 * tok], p1 = inv[2 * tok + 1];
  const float w0 = tw[2 * tok], w1 = tw[2 * tok + 1];
  half8 a = ((const half8*)(Ds + (size_t)p0 * HID))[t];
  half8 b = ((const half8*)(Ds + (size_t)p1 * HID))[t];
  float o[8];
#pragma unroll
  for (int i = 0; i < 8; i++) o[i] = w0 * (float)a[i] + w1 * (float)b[i];
  float* orow = out + (size_t)tok * HID + t * 8;
  *(float4*)orow = make_float4(o[0], o[1], o[2], o[3]);
  *(float4*)(orow + 4) = make_float4(o[4], o[5], o[6], o[7]);
}

extern "C" void kernel_launch(void* const* d_in, const int* in_sizes, int n_in,
                              void* d_out, int out_size, void* d_ws, size_t ws_size,
                              hipStream_t stream) {
  const float* x   = (const float*)d_in[0];
  const int*   ids = (const int*)d_in[1];
  const float* tw  = (const float*)d_in[2];
  const float* Wg  = (const float*)d_in[3];
  const float* Wu  = (const float*)d_in[4];
  const float* Wd  = (const float*)d_in[5];
  float* out = (float*)d_out;

  char* ws = (char*)d_ws;
  size_t p = 0;
  auto alloc = [&](size_t bytes) -> void* {
    void* r = ws + p;
    p = (p + bytes + 255) & ~(size_t)255;
    return r;
  };
  int*   tinfo  = (int*)alloc((1 + 3 * MAXTILES) * 4);
  int*   stok   = (int*)alloc(NSLOT * 4);
  int*   inv    = (int*)alloc(NSLOT * 4);
  int*   schedG = (int*)alloc(GSCHED * 4);
  int*   schedD = (int*)alloc(GSCHED * 4);
  _Float16* Xg   = (_Float16*)alloc((size_t)(NSLOT + PADROWS) * HID * 2);
  _Float16* Hb   = (_Float16*)alloc((size_t)(NSLOT + PADROWS) * INTER * 2);
  _Float16* Dsb  = (_Float16*)alloc((size_t)(NSLOT + PADROWS) * HID * 2);
  _Float16* Wg16 = (_Float16*)alloc((size_t)WELEM * 2);
  _Float16* Wu16 = (_Float16*)alloc((size_t)WELEM * 2);
  _Float16* Wd16 = (_Float16*)alloc((size_t)WELEM * 2);
  (void)ws_size; (void)in_sizes; (void)n_in; (void)out_size;

  route_kernel<<<1, 256, 0, stream>>>(ids, tw, tinfo, stok, inv, schedG, schedD);
  gather_x_kernel<<<NSLOT, 256, 0, stream>>>(x, stok, Xg);
  convert3_kernel<<<dim3(WELEM / 8 / 256, 1, 3), 256, 0, stream>>>(Wg, Wu, Wd, Wg16, Wu16, Wd16);
  gateup_kernel<<<GSCHED, 256, 0, stream>>>(Xg, Wg16, Wu16, Hb, tinfo, schedG);
  down_kernel<<<GSCHED, 256, 0, stream>>>(Hb, Wd16, Dsb, tinfo, schedD);
  combine_kernel<<<N_TOK, 256, 0, stream>>>(Dsb, inv, tw, out);
}

// Round 4
// 548.774 us; speedup vs baseline: 1.3206x; 1.3206x over previous
//
#include <hip/hip_runtime.h>
#include <stdint.h>

#define N_TOK 4096
#define TOPK  2
#define NEXP  8
#define HID   2048
#define INTER 1408
#define NSLOT (N_TOK * TOPK)     // 8192 token-expert pairs
#define PADROWS 128              // guard rows for tile-overrun reads
#define WELEM (NEXP * INTER * HID)
#define MAXTILES 72              // worst-case sum of ceil(cnt_e/128)
#define NCOL_G (INTER / 128)     // 11 col strips, gate/up
#define NCOL_D (HID / 128)       // 16 col strips, down
#define NSTRIP_G (NEXP * NCOL_G) // 88
#define NSTRIP_D (NEXP * NCOL_D) // 128
#define CAP 160                  // per-XCD-residue block capacity (worst case ~142)
#define GSCHED (8 * CAP)         // 1280 scheduled block slots per GEMM

typedef _Float16 half8 __attribute__((ext_vector_type(8)));
typedef float floatx4 __attribute__((ext_vector_type(4)));

__device__ __forceinline__ void gld_lds16(const void* g, void* l) {
  // async global->LDS, 16B/lane; LDS dest = wave-uniform base + lane*16
  __builtin_amdgcn_global_load_lds(
      (const __attribute__((address_space(1))) uint32_t*)g,
      (__attribute__((address_space(3))) uint32_t*)l, 16, 0, 0);
}

// s_waitcnt imm (gfx9): vmcnt[3:0]=b3..0, vmcnt[5:4]=b15..14, exp=b6..4, lgkm=b11..8
#define WAITCNT_VM12  0x0F7C
#define WAITCNT_VM8   0x0F78
#define WAITCNT_VM6   0x0F76
#define WAITCNT_VM4   0x0F74
#define WAITCNT_VM0   0x0F70
#define WAITCNT_LGKM0 0xC07F
#define RAW_BARRIER() asm volatile("s_barrier" ::: "memory")

// ------- routing v2: fully parallel (no serial LDS/scratch chains) -------
// sched entry: (col_strip << 16) | tile_index, -1 = dead block.
// Strip s -> XCD residue s%8 (static round-robin; per-residue tile load is
// provably <= ~142 < CAP). All row-tiles of one (expert,col-strip) B-reuse
// unit sit consecutively on ONE residue so the strip stays in that XCD's L2.
__global__ void route_kernel(const int* __restrict__ ids, const float* __restrict__ tw,
                             int* __restrict__ tinfo, int* __restrict__ stok,
                             int* __restrict__ inv,
                             int* __restrict__ schedG, int* __restrict__ schedD) {
  __shared__ int sc[NEXP][256];   // per-thread counts -> inclusive prefix
  __shared__ int eo[NEXP + 1];
  __shared__ int ft[NEXP], ntl[NEXP];
  __shared__ int te[MAXTILES];
  __shared__ int gb[NSTRIP_G], db[NSTRIP_D];
  __shared__ int s_nt;
  const int t = threadIdx.x;

  // phase 1: per-thread expert histogram (tokens t, t+256, ...)
  int lc[NEXP];
#pragma unroll
  for (int e = 0; e < NEXP; e++) lc[e] = 0;
  for (int i = 0; i < NSLOT / 256; i++) {
    int e = ids[t + 256 * i];
#pragma unroll
    for (int q = 0; q < NEXP; q++) lc[q] += (e == q) ? 1 : 0;
  }
#pragma unroll
  for (int e = 0; e < NEXP; e++) sc[e][t] = lc[e];
  __syncthreads();
  // Hillis-Steele inclusive scan over 256 threads, all 8 experts at once
  for (int d = 1; d < 256; d <<= 1) {
    int v[NEXP];
#pragma unroll
    for (int e = 0; e < NEXP; e++) v[e] = sc[e][t] + ((t >= d) ? sc[e][t - d] : 0);
    __syncthreads();
#pragma unroll
    for (int e = 0; e < NEXP; e++) sc[e][t] = v[e];
    __syncthreads();
  }
  // phase 2: expert offsets + tile counts (tiny serial, registers+few LDS ops)
  if (t == 0) {
    int run = 0, nt = 0;
#pragma unroll
    for (int e = 0; e < NEXP; e++) {
      eo[e] = run;
      int c = sc[e][255];
      run += c;
      ft[e] = nt;
      ntl[e] = (c + 127) >> 7;
      nt += ntl[e];
    }
    eo[NEXP] = run;
    s_nt = nt;
    tinfo[0] = nt;
  }
  __syncthreads();
  const int nt = s_nt;
  // phase 3: tile table, one thread per tile
  for (int i = t; i < nt; i += 256) {
    int e = 0;
#pragma unroll
    for (int q = 1; q < NEXP; q++) e = (i >= ft[q]) ? q : e;
    int r0 = (i - ft[e]) << 7;
    int c = sc[e][255];
    tinfo[1 + 3 * i] = e;
    tinfo[2 + 3 * i] = eo[e] + r0;
    tinfo[3 + 3 * i] = (c - r0 < 128) ? (c - r0) : 128;
    te[i] = e;
  }
  // phase 4: per-strip base within its residue (parallel prefix, <=16 iters)
  for (int s = t; s < NSTRIP_G; s += 256) {
    int base = 0;
    for (int s2 = (s & 7); s2 < s; s2 += 8) base += ntl[s2 / NCOL_G];
    gb[s] = base;
  }
  for (int s = t; s < NSTRIP_D; s += 256) {
    int base = 0;
    for (int s2 = (s & 7); s2 < s; s2 += 8) base += ntl[s2 >> 4];
    db[s] = base;
  }
  for (int i = t; i < GSCHED; i += 256) { schedG[i] = -1; schedD[i] = -1; }
  __syncthreads();
  // phase 5: schedule fill, one thread per (tile, col-strip) pair
  for (int j = t; j < nt * NCOL_G; j += 256) {
    int i = j / NCOL_G, cx = j % NCOL_G;
    int e = te[i];
    int s = e * NCOL_G + cx;
    int slot = gb[s] + (i - ft[e]);
    if (slot < CAP) schedG[slot * 8 + (s & 7)] = (cx << 16) | i;
  }
  for (int j = t; j < nt * NCOL_D; j += 256) {
    int i = j >> 4, cx = j & 15;
    int e = te[i];
    int s = e * NCOL_D + cx;
    int slot = db[s] + (i - ft[e]);
    if (slot < CAP) schedD[slot * 8 + (s & 7)] = (cx << 16) | i;
  }
  // phase 6: compact slot list + inverse map (same token order as the scan)
  int pos[NEXP];
#pragma unroll
  for (int e = 0; e < NEXP; e++) pos[e] = eo[e] + sc[e][t] - lc[e];
  for (int i = 0; i < NSLOT / 256; i++) {
    int s = t + 256 * i;
    int e = ids[s];
    int p = 0;
#pragma unroll
    for (int q = 0; q < NEXP; q++)
      if (e == q) p = pos[q]++;
    stok[p] = s / TOPK;
    inv[s] = p;
  }
}

// ---------------- gather tokens into contiguous fp16 A ----------------
__global__ void gather_x_kernel(const float* __restrict__ x, const int* __restrict__ stok,
                                _Float16* __restrict__ xg) {
  const int row = blockIdx.x;
  const int tok = stok[row];
  const float4* src = (const float4*)(x + (size_t)tok * HID);
  half8* dst = (half8*)(xg + (size_t)row * HID);
  const int t = threadIdx.x;
  float4 a = src[2 * t], b = src[2 * t + 1];
  half8 h;
  h[0] = (_Float16)a.x; h[1] = (_Float16)a.y; h[2] = (_Float16)a.z; h[3] = (_Float16)a.w;
  h[4] = (_Float16)b.x; h[5] = (_Float16)b.y; h[6] = (_Float16)b.z; h[7] = (_Float16)b.w;
  dst[t] = h;
}

// ---------------- fp32 -> fp16 weight conversion, all 3 matrices ----------------
__global__ void convert3_kernel(const float* __restrict__ s0, const float* __restrict__ s1,
                                const float* __restrict__ s2, _Float16* __restrict__ d0,
                                _Float16* __restrict__ d1, _Float16* __restrict__ d2) {
  const float* s = blockIdx.z == 0 ? s0 : (blockIdx.z == 1 ? s1 : s2);
  _Float16* d = blockIdx.z == 0 ? d0 : (blockIdx.z == 1 ? d1 : d2);
  const int j = (blockIdx.x * 256 + threadIdx.x) * 8;
  float4 a = *(const float4*)(s + j);
  float4 b = *(const float4*)(s + j + 4);
  half8 h;
  h[0] = (_Float16)a.x; h[1] = (_Float16)a.y; h[2] = (_Float16)a.z; h[3] = (_Float16)a.w;
  h[4] = (_Float16)b.x; h[5] = (_Float16)b.y; h[6] = (_Float16)b.z; h[7] = (_Float16)b.w;
  *(half8*)(d + j) = h;
}

// ---------------- fused gate+up GEMM with SwiGLU epilogue ----------------
// 128x128 tile, BK=32, depth-3 LDS pipeline: loads get ~2 iterations of slack,
// prefetch stays in flight across raw s_barrier (no vmcnt(0) drain mid-loop).
// launch_bounds(256,2): r3's (256,3) forced VGPR 84 -> K-loop spills (WRITE 2x).
__global__ __launch_bounds__(256, 2) void gateup_kernel(
    const _Float16* __restrict__ A, const _Float16* __restrict__ Bg,
    const _Float16* __restrict__ Bu, _Float16* __restrict__ H,
    const int* __restrict__ tinfo, const int* __restrict__ sched) {
  const int ent = sched[blockIdx.x];
  if (ent < 0) return;
  const int ti   = ent & 0xFFFF;
  const int e    = tinfo[1 + 3 * ti];
  const int row0 = tinfo[2 + 3 * ti];
  const int mrem = tinfo[3 + 3 * ti];
  const int col0 = (ent >> 16) * 128;
  const _Float16* Bge = Bg + (size_t)e * INTER * HID;
  const _Float16* Bue = Bu + (size_t)e * INTER * HID;

  __shared__ __align__(16) _Float16 As[3][128 * 32];
  __shared__ __align__(16) _Float16 Bgs[3][128 * 32];
  __shared__ __align__(16) _Float16 Bus[3][128 * 32];

  const int tid = threadIdx.x;
  const int wave = tid >> 6, lane = tid & 63;
  const int quad = lane >> 4, l16 = lane & 15;
  const int wm = (wave >> 1) * 64, wn = (wave & 1) * 64;

  const int bo0 = wave * 2048 + lane * 16, bo1 = bo0 + 1024;
  const int ar0 = bo0 >> 6, ak0 = (bo0 & 63) >> 1;
  const int ar1 = bo1 >> 6, ak1 = (bo1 & 63) >> 1;
  const _Float16* Ab0 = A + (size_t)(row0 + ar0) * HID + ak0;
  const _Float16* Ab1 = A + (size_t)(row0 + ar1) * HID + ak1;
  const _Float16* Bg0 = Bge + (size_t)(col0 + ar0) * HID + ak0;
  const _Float16* Bg1 = Bge + (size_t)(col0 + ar1) * HID + ak1;
  const _Float16* Bu0 = Bue + (size_t)(col0 + ar0) * HID + ak0;
  const _Float16* Bu1 = Bue + (size_t)(col0 + ar1) * HID + ak1;

  floatx4 ag[4][4], au[4][4];
#pragma unroll
  for (int a = 0; a < 4; a++)
#pragma unroll
    for (int b = 0; b < 4; b++) {
      ag[a][b] = (floatx4){0.f, 0.f, 0.f, 0.f};
      au[a][b] = (floatx4){0.f, 0.f, 0.f, 0.f};
    }

  auto stage = [&](int kt, int buf) {  // 6 vmem issues per wave
    const int k0 = kt * 32;
    char* as = (char*)(As[buf]) + wave * 2048;
    char* bg = (char*)(Bgs[buf]) + wave * 2048;
    char* bu = (char*)(Bus[buf]) + wave * 2048;
    gld_lds16(Ab0 + k0, as);
    gld_lds16(Ab1 + k0, as + 1024);
    gld_lds16(Bg0 + k0, bg);
    gld_lds16(Bg1 + k0, bg + 1024);
    gld_lds16(Bu0 + k0, bu);
    gld_lds16(Bu1 + k0, bu + 1024);
  };

  const int NKI = HID / 32;  // 64
  stage(0, 0);
  stage(1, 1);
  stage(2, 2);
  int buf = 0;
  for (int kt = 0; kt < NKI; ++kt) {
    const int rem = NKI - 1 - kt;
    if (rem >= 2)      __builtin_amdgcn_s_waitcnt(WAITCNT_VM12);
    else if (rem == 1) __builtin_amdgcn_s_waitcnt(WAITCNT_VM6);
    else               __builtin_amdgcn_s_waitcnt(WAITCNT_VM0);
    RAW_BARRIER();  // stage(kt) visible everywhere; kt+1,kt+2 stay in flight
    half8 af[4], bgf[4], buf_[4];
#pragma unroll
    for (int i = 0; i < 4; ++i) {
      af[i]   = *(const half8*)(As[buf]  + (wm + i * 16 + l16) * 32 + quad * 8);
      bgf[i]  = *(const half8*)(Bgs[buf] + (wn + i * 16 + l16) * 32 + quad * 8);
      buf_[i] = *(const half8*)(Bus[buf] + (wn + i * 16 + l16) * 32 + quad * 8);
    }
    __builtin_amdgcn_s_waitcnt(WAITCNT_LGKM0);
    RAW_BARRIER();                           // all waves done reading buf
    if (kt + 3 < NKI) stage(kt + 3, buf);    // safe to overwrite now
#pragma unroll
    for (int mi = 0; mi < 4; ++mi)
#pragma unroll
      for (int ni = 0; ni < 4; ++ni) {
        ag[mi][ni] = __builtin_amdgcn_mfma_f32_16x16x32_f16(af[mi], bgf[ni], ag[mi][ni], 0, 0, 0);
        au[mi][ni] = __builtin_amdgcn_mfma_f32_16x16x32_f16(af[mi], buf_[ni], au[mi][ni], 0, 0, 0);
      }
    buf = (buf == 2) ? 0 : buf + 1;
  }

  // D mapping (m89): col = lane&15, row = quad*4 + reg
#pragma unroll
  for (int mi = 0; mi < 4; ++mi)
#pragma unroll
    for (int r = 0; r < 4; ++r) {
      const int rm = wm + mi * 16 + quad * 4 + r;
      if (rm < mrem) {
        _Float16* hrow = H + (size_t)(row0 + rm) * INTER + col0 + wn;
#pragma unroll
        for (int ni = 0; ni < 4; ++ni) {
          float g = ag[mi][ni][r], u = au[mi][ni][r];
          float s = 1.0f / (1.0f + __expf(-g));
          hrow[ni * 16 + l16] = (_Float16)(g * s * u);
        }
      }
    }
}

// ---------------- down GEMM, plain per-slot fp16 store ----------------
__global__ __launch_bounds__(256, 2) void down_kernel(
    const _Float16* __restrict__ A, const _Float16* __restrict__ B,
    _Float16* __restrict__ Ds, const int* __restrict__ tinfo,
    const int* __restrict__ sched) {
  const int ent = sched[blockIdx.x];
  if (ent < 0) return;
  const int ti   = ent & 0xFFFF;
  const int e    = tinfo[1 + 3 * ti];
  const int row0 = tinfo[2 + 3 * ti];
  const int mrem = tinfo[3 + 3 * ti];
  const int col0 = (ent >> 16) * 128;
  const _Float16* Be = B + (size_t)e * HID * INTER;

  __shared__ __align__(16) _Float16 As[3][128 * 32];
  __shared__ __align__(16) _Float16 Bs[3][128 * 32];

  const int tid = threadIdx.x;
  const int wave = tid >> 6, lane = tid & 63;
  const int quad = lane >> 4, l16 = lane & 15;
  const int wm = (wave >> 1) * 64, wn = (wave & 1) * 64;

  const int bo0 = wave * 2048 + lane * 16, bo1 = bo0 + 1024;
  const int ar0 = bo0 >> 6, ak0 = (bo0 & 63) >> 1;
  const int ar1 = bo1 >> 6, ak1 = (bo1 & 63) >> 1;
  const _Float16* Ab0 = A + (size_t)(row0 + ar0) * INTER + ak0;
  const _Float16* Ab1 = A + (size_t)(row0 + ar1) * INTER + ak1;
  const _Float16* Bb0 = Be + (size_t)(col0 + ar0) * INTER + ak0;
  const _Float16* Bb1 = Be + (size_t)(col0 + ar1) * INTER + ak1;

  floatx4 acc[4][4];
#pragma unroll
  for (int a = 0; a < 4; a++)
#pragma unroll
    for (int b = 0; b < 4; b++) acc[a][b] = (floatx4){0.f, 0.f, 0.f, 0.f};

  auto stage = [&](int kt, int buf) {  // 4 vmem issues per wave
    const int k0 = kt * 32;
    char* as = (char*)(As[buf]) + wave * 2048;
    char* bs = (char*)(Bs[buf]) + wave * 2048;
    gld_lds16(Ab0 + k0, as);
    gld_lds16(Ab1 + k0, as + 1024);
    gld_lds16(Bb0 + k0, bs);
    gld_lds16(Bb1 + k0, bs + 1024);
  };

  const int NKI = INTER / 32;  // 44
  stage(0, 0);
  stage(1, 1);
  stage(2, 2);
  int buf = 0;
  for (int kt = 0; kt < NKI; ++kt) {
    const int rem = NKI - 1 - kt;
    if (rem >= 2)      __builtin_amdgcn_s_waitcnt(WAITCNT_VM8);
    else if (rem == 1) __builtin_amdgcn_s_waitcnt(WAITCNT_VM4);
    else               __builtin_amdgcn_s_waitcnt(WAITCNT_VM0);
    RAW_BARRIER();
    half8 af[4], bf[4];
#pragma unroll
    for (int i = 0; i < 4; ++i) {
      af[i] = *(const half8*)(As[buf] + (wm + i * 16 + l16) * 32 + quad * 8);
      bf[i] = *(const half8*)(Bs[buf] + (wn + i * 16 + l16) * 32 + quad * 8);
    }
    __builtin_amdgcn_s_waitcnt(WAITCNT_LGKM0);
    RAW_BARRIER();
    if (kt + 3 < NKI) stage(kt + 3, buf);
#pragma unroll
    for (int mi = 0; mi < 4; ++mi)
#pragma unroll
      for (int ni = 0; ni < 4; ++ni)
        acc[mi][ni] = __builtin_amdgcn_mfma_f32_16x16x32_f16(af[mi], bf[ni], acc[mi][ni], 0, 0, 0);
    buf = (buf == 2) ? 0 : buf + 1;
  }

#pragma unroll
  for (int mi = 0; mi < 4; ++mi)
#pragma unroll
    for (int r = 0; r < 4; ++r) {
      const int rm = wm + mi * 16 + quad * 4 + r;
      if (rm < mrem) {
        _Float16* drow = Ds + (size_t)(row0 + rm) * HID + col0 + wn;
#pragma unroll
        for (int ni = 0; ni < 4; ++ni) drow[ni * 16 + l16] = (_Float16)acc[mi][ni][r];
      }
    }
}

// ---------------- combine: out[tok] = w0*Ds[p0] + w1*Ds[p1] ----------------
__global__ void combine_kernel(const _Float16* __restrict__ Ds, const int* __restrict__ inv,
                               const float* __restrict__ tw, float* __restrict__ out) {
  const int tok = blockIdx.x, t = threadIdx.x;
  const int p0 = inv[2 * tok], p1 = inv[2 * tok + 1];
  const float w0 = tw[2 * tok], w1 = tw[2 * tok + 1];
  half8 a = ((const half8*)(Ds + (size_t)p0 * HID))[t];
  half8 b = ((const half8*)(Ds + (size_t)p1 * HID))[t];
  float o[8];
#pragma unroll
  for (int i = 0; i < 8; i++) o[i] = w0 * (float)a[i] + w1 * (float)b[i];
  float* orow = out + (size_t)tok * HID + t * 8;
  *(float4*)orow = make_float4(o[0], o[1], o[2], o[3]);
  *(float4*)(orow + 4) = make_float4(o[4], o[5], o[6], o[7]);
}

extern "C" void kernel_launch(void* const* d_in, const int* in_sizes, int n_in,
                              void* d_out, int out_size, void* d_ws, size_t ws_size,
                              hipStream_t stream) {
  const float* x   = (const float*)d_in[0];
  const int*   ids = (const int*)d_in[1];
  const float* tw  = (const float*)d_in[2];
  const float* Wg  = (const float*)d_in[3];
  const float* Wu  = (const float*)d_in[4];
  const float* Wd  = (const float*)d_in[5];
  float* out = (float*)d_out;

  char* ws = (char*)d_ws;
  size_t p = 0;
  auto alloc = [&](size_t bytes) -> void* {
    void* r = ws + p;
    p = (p + bytes + 255) & ~(size_t)255;
    return r;
  };
  int*   tinfo  = (int*)alloc((1 + 3 * MAXTILES) * 4);
  int*   stok   = (int*)alloc(NSLOT * 4);
  int*   inv    = (int*)alloc(NSLOT * 4);
  int*   schedG = (int*)alloc(GSCHED * 4);
  int*   schedD = (int*)alloc(GSCHED * 4);
  _Float16* Xg   = (_Float16*)alloc((size_t)(NSLOT + PADROWS) * HID * 2);
  _Float16* Hb   = (_Float16*)alloc((size_t)(NSLOT + PADROWS) * INTER * 2);
  _Float16* Dsb  = (_Float16*)alloc((size_t)(NSLOT + PADROWS) * HID * 2);
  _Float16* Wg16 = (_Float16*)alloc((size_t)WELEM * 2);
  _Float16* Wu16 = (_Float16*)alloc((size_t)WELEM * 2);
  _Float16* Wd16 = (_Float16*)alloc((size_t)WELEM * 2);
  (void)ws_size; (void)in_sizes; (void)n_in; (void)out_size;

  route_kernel<<<1, 256, 0, stream>>>(ids, tw, tinfo, stok, inv, schedG, schedD);
  gather_x_kernel<<<NSLOT, 256, 0, stream>>>(x, stok, Xg);
  convert3_kernel<<<dim3(WELEM / 8 / 256, 1, 3), 256, 0, stream>>>(Wg, Wu, Wd, Wg16, Wu16, Wd16);
  gateup_kernel<<<GSCHED, 256, 0, stream>>>(Xg, Wg16, Wu16, Hb, tinfo, schedG);
  down_kernel<<<GSCHED, 256, 0, stream>>>(Hb, Wd16, Dsb, tinfo, schedD);
  combine_kernel<<<N_TOK, 256, 0, stream>>>(Dsb, inv, tw, out);
}